// Round 15
// baseline (737.591 us; speedup 1.0000x reference)
//
#include <hip/hip_runtime.h>
#include <cmath>

#define NS 51
#define ND 50
#define PLANE 1048576            // 1024*1024
#define DOG_ELEMS (ND * PLANE)   // 52428800
#define WPSTRIDE 160             // padded 1-D kernel: 17 zeros | taps | zeros
#define NPF 6                    // prefetch float4 regs/thread (176*17/512 -> 6)

// ---------------- K0: extract normalized 1-D kernels + radii --------------------
__global__ void dog_prep(const float* __restrict__ weight,
                         float* __restrict__ wp,
                         int* __restrict__ rarr, int S) {
    int i = blockIdx.x;
    int t = threadIdx.x;
    int R = (S - 1) >> 1;
    const float* row = weight + ((size_t)i * S + R) * S;   // center row of scale i
    __shared__ float sr[128];
    __shared__ float ssum;
    __shared__ int spad;
    if (t < S) sr[t] = row[t];
    for (int j = t; j < WPSTRIDE; j += blockDim.x) wp[i * WPSTRIDE + j] = 0.f;
    __syncthreads();
    if (t == 0) {
        float sum = 0.f;
        for (int j = 0; j < S; ++j) sum += sr[j];
        int pad = 0;
        while (pad < R && sr[pad] == 0.f) ++pad;
        ssum = sum; spad = pad;
        rarr[i] = R - pad;
    }
    __syncthreads();
    int pad = spad;
    int r = R - pad;
    float inv = 1.f / ssum;
    for (int j = t; j <= 2 * r; j += blockDim.x)
        wp[i * WPSTRIDE + 17 + j] = sr[pad + j] * inv;
}

// ---------------- K1: horizontal blur (unchanged from R14) ----------------------
__global__ __launch_bounds__(256) void dog_hblur(
        const float* __restrict__ in, float* __restrict__ tmpH,
        const float* __restrict__ wp, const int* __restrict__ rarr) {
    const int lo_t[5] = {0, 17, 28, 37, 44};
    const int hi_t[5] = {17, 28, 37, 44, 51};
    int t = threadIdx.x;
    int grp = t >> 7;
    int tl = t & 127;
    int y = (blockIdx.x << 1) | grp;
    int zc = blockIdx.y;
    __shared__ float srow[2][1284];                 // 321 swizzled float4 slots
    const float* inrow = in + ((size_t)y << 10);
    for (int f = tl; f < 286; f += 128) {           // elements 4f-56 .. 4f-53
        int xg = (f << 2) - 56;
        float4 v = make_float4(0.f, 0.f, 0.f, 0.f);
        if (xg >= 0 && xg <= 1020) {
            v = *(const float4*)(inrow + xg);
        } else {
            float vv[4];
#pragma unroll
            for (int c = 0; c < 4; ++c) {
                int g = xg + c;
                vv[c] = ((unsigned)g < 1024u) ? inrow[g] : 0.f;
            }
            v = make_float4(vv[0], vv[1], vv[2], vv[3]);
        }
        int fs = f + (f >> 3);                      // swizzled float4 index
        *(float4*)&srow[grp][fs << 2] = v;
    }
    __syncthreads();
    const float* s = srow[grp];
    for (int i = lo_t[zc]; i < hi_t[zc]; ++i) {
        int r = rarr[i];
        int c0 = 56 - r;
        int d = c0 & 7;
        int c0a = c0 - d;
        const float* __restrict__ w2 = wp + i * WPSTRIDE + 17 - d;
        int mcount = ((2 * r + d + 15) >> 3) << 3;  // >= 2r+d+8, mult of 8
        float acc[8];
#pragma unroll
        for (int k = 0; k < 8; ++k) acc[k] = 0.f;
        int ft = (c0a >> 2) + (tl << 1);            // base float4 index
        for (int m = 0; m < mcount; m += 8) {
            int f  = ft + (m >> 2);
            int fa = f + (f >> 3);
            int fb = (f + 1) + ((f + 1) >> 3);
            float4 va = *(const float4*)&s[fa << 2];
            float4 vb = *(const float4*)&s[fb << 2];
            float v[8] = {va.x, va.y, va.z, va.w, vb.x, vb.y, vb.z, vb.w};
#pragma unroll
            for (int j2 = 0; j2 < 8; ++j2)
#pragma unroll
                for (int k = 0; k < 8; ++k)
                    acc[k] = fmaf(w2[m + j2 - k], v[j2], acc[k]);
        }
        float* o = tmpH + (((size_t)i) << 20) + ((size_t)y << 10) + (tl << 3);
        *(float4*)o       = make_float4(acc[0], acc[1], acc[2], acc[3]);
        *(float4*)(o + 4) = make_float4(acc[4], acc[5], acc[6], acc[7]);
    }
}

// ---------------- K2: fused vconv + DoG + 3x3x3 pool + epilogue -----------------
// ONE change vs R14 (T14 async-STAGE split): staging is reg-double-buffered.
// Per scale: barrier -> ds_write the ALREADY-LOADED reg batch -> barrier ->
// issue next scale's global loads into regs (no wait) -> conv + epilogue.
// Prefetch latency hides under conv; only exposed wait is vmcnt before
// ds_write, which follows a full conv phase.

#define FMAG(W, V, MM) do {                                                       \
_Pragma("unroll")                                                                 \
    for (int j_ = 0; j_ < 8; ++j_)                                                \
_Pragma("unroll")                                                                 \
        for (int k_ = 0; k_ < 10; ++k_)                                           \
            acc[k_] = fmaf((W)[17 + (MM) + j_ - k_], V[j_], acc[k_]);             \
    } while (0)

// issue global loads for scale ii into pv[] (no waits here)
#define PREF(ii) do {                                                             \
    int r2_ = rarr[ii];                                                           \
    const float* pl_ = tmpH + ((size_t)(ii) << 20);                               \
    int mc2_ = ((2 * r2_ + 17) >> 3) << 3;                                        \
    nf4c = (mc2_ + 64) * 17;                                                      \
    int gyb_ = (ybg << 6) - 1 - r2_;                                              \
_Pragma("unroll")                                                                 \
    for (int k_ = 0; k_ < NPF; ++k_) {                                            \
        int e_ = t + (k_ << 9);                                                   \
        float4 v_ = make_float4(0.f, 0.f, 0.f, 0.f);                              \
        if (e_ < nf4c) {                                                          \
            int row_ = e_ / 17, c_ = e_ - row_ * 17;                              \
            int gy_ = gyb_ + row_;                                                \
            int gx_ = xa + (c_ << 2);                                             \
            if ((unsigned)gy_ < 1024u) {                                          \
                const float* rp_ = pl_ + ((size_t)gy_ << 10);                     \
                if ((unsigned)gx_ <= 1020u) {                                     \
                    v_ = *(const float4*)(rp_ + gx_);                             \
                } else {                                                          \
                    float vv_[4];                                                 \
_Pragma("unroll")                                                                 \
                    for (int cc_ = 0; cc_ < 4; ++cc_) {                           \
                        int g_ = gx_ + cc_;                                       \
                        vv_[cc_] = ((unsigned)g_ < 1024u) ? rp_[g_] : 0.f;        \
                    }                                                             \
                    v_ = make_float4(vv_[0], vv_[1], vv_[2], vv_[3]);             \
                }                                                                 \
            }                                                                     \
        }                                                                         \
        pv[k_] = v_;                                                              \
    } } while (0)

__global__ __launch_bounds__(512, 6) void dog_fused(
        const float* __restrict__ tmpH, float* __restrict__ out,
        const float* __restrict__ wp, const int* __restrict__ rarr,
        const float* __restrict__ sigmas, const float* __restrict__ thr_p) {
    const int jlo_t[5] = {0, 17, 28, 37, 44};
    const int jhi_t[5] = {16, 27, 36, 43, 49};
    int p = blockIdx.x;                   // 0..1407
    int xcd = p & 7;
    int q = p >> 3;                       // 0..175
    int c8 = q >> 4;                      // 0..10
    int ybg = q & 15;                     // 0..15  (same-XCD consecutive y-blocks)
    int combo = (c8 << 3) | xcd;          // 0..87
    if (combo >= 85) return;              // pad blocks
    int wx = combo % 17;                  // 0..16
    int zc = combo / 17;                  // 0..4
    int t = threadIdx.x;
    int lane = t & 63;
    int wv = t >> 6;                      // 0..7
    int y0u = __builtin_amdgcn_readfirstlane((ybg << 6) + (wv << 3));
    int x0 = wx * 62 - 1;
    int x = x0 + lane;                    // -1 .. 1054
    int xa = x0 & ~3;                     // 4-aligned stage base col
    int lx = (x0 - xa) + lane;            // lane's col in stage [0..66]
    bool xok = ((unsigned)x < 1024u);
    float thr = thr_p[0];
    const float NEG = -__builtin_huge_valf();

    __shared__ float stage[176 * 68];     // 47.9 KB

    int jlo = jlo_t[zc], jhi = jhi_t[zc];
    int istart = jlo > 0 ? jlo - 1 : 0;
    int iend = (jhi + 2 < 50) ? jhi + 2 : 50;

    float gprev[10], A[8], B[8], Dprev[8];
#pragma unroll
    for (int k = 0; k < 10; ++k) gprev[k] = 0.f;
#pragma unroll
    for (int k = 0; k < 8; ++k) { A[k] = NEG; B[k] = NEG; Dprev[k] = 0.f; }

    float4 pv[NPF];
    int nf4c;                             // nf4 of the scale currently in pv[]
    PREF(istart);

    for (int i = istart; i <= iend; ++i) {
        int r = rarr[i];
        const float* __restrict__ w = wp + i * WPSTRIDE;
        int mcount = ((2 * r + 17) >> 3) << 3;       // >= 2r+10, mult of 8
        __syncthreads();                             // prev conv reads done
        int nf4 = nf4c;
#pragma unroll
        for (int k = 0; k < NPF; ++k) {              // regs -> LDS (vmcnt wait here)
            int e = t + (k << 9);
            if (e < nf4) {
                int row = e / 17, c = e - row * 17;
                *(float4*)(stage + row * 68 + (c << 2)) = pv[k];
            }
        }
        __syncthreads();                             // stage visible
        if (i < iend) PREF(i + 1);                   // issue next loads, no wait
        float acc[10];
#pragma unroll
        for (int k = 0; k < 10; ++k) acc[k] = 0.f;
        int base = (wv << 3) * 68 + lx;
        for (int m = 0; m < mcount; m += 8) {
            float v[8];
#pragma unroll
            for (int j = 0; j < 8; ++j) v[j] = stage[base + (m + j) * 68];
            FMAG(w, v, m);
        }
        // ---- epilogue for scale i ----
        if (i > istart) {
            int d = i - 1;
            float sg = sigmas[d];
#pragma unroll
            for (int k = 0; k < 10; ++k) {           // DoG; -inf outside image
                int gy = y0u - 1 + k;
                bool ok = xok && ((unsigned)gy < 1024u);
                gprev[k] = ok ? (gprev[k] - acc[k]) * sg : NEG;
            }
            float ym[8];
#pragma unroll
            for (int k = 0; k < 8; ++k)
                ym[k] = fmaxf(fmaxf(gprev[k], gprev[k + 1]), gprev[k + 2]);
            if (d - 1 >= jlo) {                      // emit j = d-1
                float pooled[8];
#pragma unroll
                for (int k = 0; k < 8; ++k) {
                    float pn = fmaxf(B[k], ym[k]);
                    float l  = __shfl_up(pn, 1);
                    float rr = __shfl_down(pn, 1);
                    pooled[k] = fmaxf(fmaxf(l, rr), pn);
                }
                if (xok && lane >= 1 && lane <= 62) {
                    int j = d - 1;
#pragma unroll
                    for (int k = 0; k < 8; ++k) {
                        float lm = fmaxf(pooled[k] + thr, 0.f);
                        float sm = 1.f - lm + Dprev[k] + thr;
                        float* orow = out + (((size_t)j << 20)
                                     + ((size_t)(y0u + k) << 10));
                        __builtin_nontemporal_store(lm, orow + x);
                        __builtin_nontemporal_store(sm, orow + DOG_ELEMS + x);
                    }
                }
            }
#pragma unroll
            for (int k = 0; k < 8; ++k) {
                B[k] = fmaxf(A[k], ym[k]);
                A[k] = ym[k];
                Dprev[k] = gprev[k + 1];             // dog center rows
            }
        }
#pragma unroll
        for (int k = 0; k < 10; ++k) gprev[k] = acc[k];
    }
    if (jhi == 49) {                                 // tail: j=49 (ym_50 = -inf)
        float pooled[8];
#pragma unroll
        for (int k = 0; k < 8; ++k) {
            float pn = B[k];
            float l  = __shfl_up(pn, 1);
            float rr = __shfl_down(pn, 1);
            pooled[k] = fmaxf(fmaxf(l, rr), pn);
        }
        if (xok && lane >= 1 && lane <= 62) {
#pragma unroll
            for (int k = 0; k < 8; ++k) {
                float lm = fmaxf(pooled[k] + thr, 0.f);
                float sm = 1.f - lm + Dprev[k] + thr;
                float* orow = out + (((size_t)49 << 20)
                             + ((size_t)(y0u + k) << 10));
                __builtin_nontemporal_store(lm, orow + x);
                __builtin_nontemporal_store(sm, orow + DOG_ELEMS + x);
            }
        }
    }
}

extern "C" void kernel_launch(void* const* d_in, const int* in_sizes, int n_in,
                              void* d_out, int out_size, void* d_ws, size_t ws_size,
                              hipStream_t stream) {
    const float* input  = (const float*)d_in[0];
    const float* weight = (const float*)d_in[1];
    const float* sigmas = (const float*)d_in[2];
    const float* thr    = (const float*)d_in[3];
    float* out = (float*)d_out;

    int S = 103;
    if (n_in > 1 && in_sizes[1] >= NS) {
        int s2 = in_sizes[1] / NS;
        S = (int)(sqrt((double)s2) + 0.5);
    }

    size_t need = ((size_t)NS * PLANE + NS * WPSTRIDE + 64) * 4 + 256;
    if (ws_size < need) return;   // insufficient scratch -> visible validation failure

    float* tmpH = (float*)d_ws;                    // 51 planes (214 MB)
    float* wp   = tmpH + (size_t)NS * PLANE;       // 51 * 160 floats
    int*   rarr = (int*)(wp + NS * WPSTRIDE);      // 51 ints (64 slots)

    dog_prep <<<NS, 128, 0, stream>>>(weight, wp, rarr, S);
    dog_hblur<<<dim3(512, 5), 256, 0, stream>>>(input, tmpH, wp, rarr);
    dog_fused<<<1408, 512, 0, stream>>>(tmpH, out, wp, rarr, sigmas, thr);
}

// Round 16
// 629.514 us; speedup vs baseline: 1.1717x; 1.1717x over previous
//
#include <hip/hip_runtime.h>
#include <cmath>

#define NS 51
#define ND 50
#define PLANE 1048576            // 1024*1024
#define DOG_ELEMS (ND * PLANE)   // 52428800
#define WPSTRIDE 160             // padded 1-D kernel: 17 zeros | taps | zeros

// ---------------- K0: extract normalized 1-D kernels + radii --------------------
__global__ void dog_prep(const float* __restrict__ weight,
                         float* __restrict__ wp,
                         int* __restrict__ rarr, int S) {
    int i = blockIdx.x;
    int t = threadIdx.x;
    int R = (S - 1) >> 1;
    const float* row = weight + ((size_t)i * S + R) * S;   // center row of scale i
    __shared__ float sr[128];
    __shared__ float ssum;
    __shared__ int spad;
    if (t < S) sr[t] = row[t];
    for (int j = t; j < WPSTRIDE; j += blockDim.x) wp[i * WPSTRIDE + j] = 0.f;
    __syncthreads();
    if (t == 0) {
        float sum = 0.f;
        for (int j = 0; j < S; ++j) sum += sr[j];
        int pad = 0;
        while (pad < R && sr[pad] == 0.f) ++pad;
        ssum = sum; spad = pad;
        rarr[i] = R - pad;
    }
    __syncthreads();
    int pad = spad;
    int r = R - pad;
    float inv = 1.f / ssum;
    for (int j = t; j <= 2 * r; j += blockDim.x)
        wp[i * WPSTRIDE + 17 + j] = sr[pad + j] * inv;
}

// ---------------- K1: horizontal blur (unchanged from R14) ----------------------
__global__ __launch_bounds__(256) void dog_hblur(
        const float* __restrict__ in, float* __restrict__ tmpH,
        const float* __restrict__ wp, const int* __restrict__ rarr) {
    const int lo_t[5] = {0, 17, 28, 37, 44};
    const int hi_t[5] = {17, 28, 37, 44, 51};
    int t = threadIdx.x;
    int grp = t >> 7;
    int tl = t & 127;
    int y = (blockIdx.x << 1) | grp;
    int zc = blockIdx.y;
    __shared__ float srow[2][1284];                 // 321 swizzled float4 slots
    const float* inrow = in + ((size_t)y << 10);
    for (int f = tl; f < 286; f += 128) {           // elements 4f-56 .. 4f-53
        int xg = (f << 2) - 56;
        float4 v = make_float4(0.f, 0.f, 0.f, 0.f);
        if (xg >= 0 && xg <= 1020) {
            v = *(const float4*)(inrow + xg);
        } else {
            float vv[4];
#pragma unroll
            for (int c = 0; c < 4; ++c) {
                int g = xg + c;
                vv[c] = ((unsigned)g < 1024u) ? inrow[g] : 0.f;
            }
            v = make_float4(vv[0], vv[1], vv[2], vv[3]);
        }
        int fs = f + (f >> 3);                      // swizzled float4 index
        *(float4*)&srow[grp][fs << 2] = v;
    }
    __syncthreads();
    const float* s = srow[grp];
    for (int i = lo_t[zc]; i < hi_t[zc]; ++i) {
        int r = rarr[i];
        int c0 = 56 - r;
        int d = c0 & 7;
        int c0a = c0 - d;
        const float* __restrict__ w2 = wp + i * WPSTRIDE + 17 - d;
        int mcount = ((2 * r + d + 15) >> 3) << 3;  // >= 2r+d+8, mult of 8
        float acc[8];
#pragma unroll
        for (int k = 0; k < 8; ++k) acc[k] = 0.f;
        int ft = (c0a >> 2) + (tl << 1);            // base float4 index
        for (int m = 0; m < mcount; m += 8) {
            int f  = ft + (m >> 2);
            int fa = f + (f >> 3);
            int fb = (f + 1) + ((f + 1) >> 3);
            float4 va = *(const float4*)&s[fa << 2];
            float4 vb = *(const float4*)&s[fb << 2];
            float v[8] = {va.x, va.y, va.z, va.w, vb.x, vb.y, vb.z, vb.w};
#pragma unroll
            for (int j2 = 0; j2 < 8; ++j2)
#pragma unroll
                for (int k = 0; k < 8; ++k)
                    acc[k] = fmaf(w2[m + j2 - k], v[j2], acc[k]);
        }
        float* o = tmpH + (((size_t)i) << 20) + ((size_t)y << 10) + (tl << 3);
        *(float4*)o       = make_float4(acc[0], acc[1], acc[2], acc[3]);
        *(float4*)(o + 4) = make_float4(acc[4], acc[5], acc[6], acc[7]);
    }
}

// ---------------- K2: fused vconv + DoG + 3x3x3 pool + epilogue -----------------
// R15's T14 split, spill-proofed: pv0..pv5 are NAMED scalars (no array ->
// nothing to demote to scratch); stores are UNCONDITIONAL (load index clamped
// to nf4c-1; stage padded to 181 rows so unclamped store positions are in
// bounds; rows >= nrows never read). Per scale: barrier -> ds_write regs ->
// barrier -> issue next scale's loads (no wait) -> conv + epilogue.

#define FMAG(W, V, MM) do {                                                       \
_Pragma("unroll")                                                                 \
    for (int j_ = 0; j_ < 8; ++j_)                                                \
_Pragma("unroll")                                                                 \
        for (int k_ = 0; k_ < 10; ++k_)                                           \
            acc[k_] = fmaf((W)[17 + (MM) + j_ - k_], V[j_], acc[k_]);             \
    } while (0)

#define PREF1(PV, KK) do {                                                        \
    int e_ = t + ((KK) << 9);                                                     \
    int ec_ = e_ < nf4c ? e_ : nf4c - 1;                                          \
    int row_ = ec_ / 17, c_ = ec_ - row_ * 17;                                    \
    int gy_ = gyb + row_;                                                         \
    int gx_ = xa + (c_ << 2);                                                     \
    float4 v_ = make_float4(0.f, 0.f, 0.f, 0.f);                                  \
    if ((unsigned)gy_ < 1024u) {                                                  \
        const float* rp_ = plc + ((size_t)gy_ << 10);                             \
        if ((unsigned)gx_ <= 1020u) {                                             \
            v_ = *(const float4*)(rp_ + gx_);                                     \
        } else {                                                                  \
            float vv_[4];                                                         \
_Pragma("unroll")                                                                 \
            for (int cc_ = 0; cc_ < 4; ++cc_) {                                   \
                int g_ = gx_ + cc_;                                               \
                vv_[cc_] = ((unsigned)g_ < 1024u) ? rp_[g_] : 0.f;                \
            }                                                                     \
            v_ = make_float4(vv_[0], vv_[1], vv_[2], vv_[3]);                     \
        }                                                                         \
    }                                                                             \
    PV = v_;                                                                      \
} while (0)

#define PREF(ii) do {                                                             \
    int r2_ = rarr[ii];                                                           \
    plc = tmpH + ((size_t)(ii) << 20);                                            \
    int mc2_ = ((2 * r2_ + 17) >> 3) << 3;                                        \
    nf4c = (mc2_ + 64) * 17;                                                      \
    gyb = (ybg << 6) - 1 - r2_;                                                   \
    PREF1(pv0, 0); PREF1(pv1, 1); PREF1(pv2, 2);                                  \
    PREF1(pv3, 3); PREF1(pv4, 4); PREF1(pv5, 5);                                  \
} while (0)

#define STOREPV(PV, KK) do {                                                      \
    int e_ = t + ((KK) << 9);                                                     \
    int row_ = e_ / 17, c_ = e_ - row_ * 17;                                      \
    *(float4*)(stage + row_ * 68 + (c_ << 2)) = PV;                               \
} while (0)

__global__ __launch_bounds__(512, 6) void dog_fused(
        const float* __restrict__ tmpH, float* __restrict__ out,
        const float* __restrict__ wp, const int* __restrict__ rarr,
        const float* __restrict__ sigmas, const float* __restrict__ thr_p) {
    const int jlo_t[5] = {0, 17, 28, 37, 44};
    const int jhi_t[5] = {16, 27, 36, 43, 49};
    int p = blockIdx.x;                   // 0..1407
    int xcd = p & 7;
    int q = p >> 3;                       // 0..175
    int c8 = q >> 4;                      // 0..10
    int ybg = q & 15;                     // 0..15  (same-XCD consecutive y-blocks)
    int combo = (c8 << 3) | xcd;          // 0..87
    if (combo >= 85) return;              // pad blocks
    int wx = combo % 17;                  // 0..16
    int zc = combo / 17;                  // 0..4
    int t = threadIdx.x;
    int lane = t & 63;
    int wv = t >> 6;                      // 0..7
    int y0u = __builtin_amdgcn_readfirstlane((ybg << 6) + (wv << 3));
    int x0 = wx * 62 - 1;
    int x = x0 + lane;                    // -1 .. 1054
    int xa = x0 & ~3;                     // 4-aligned stage base col
    int lx = (x0 - xa) + lane;            // lane's col in stage [0..66]
    bool xok = ((unsigned)x < 1024u);
    float thr = thr_p[0];
    const float NEG = -__builtin_huge_valf();

    __shared__ float stage[181 * 68];     // 49.2 KB (181 rows: unconditional stores)

    int jlo = jlo_t[zc], jhi = jhi_t[zc];
    int istart = jlo > 0 ? jlo - 1 : 0;
    int iend = (jhi + 2 < 50) ? jhi + 2 : 50;

    float gprev[10], A[8], B[8], Dprev[8];
#pragma unroll
    for (int k = 0; k < 10; ++k) gprev[k] = 0.f;
#pragma unroll
    for (int k = 0; k < 8; ++k) { A[k] = NEG; B[k] = NEG; Dprev[k] = 0.f; }

    float4 pv0, pv1, pv2, pv3, pv4, pv5;  // named prefetch regs (spill-proof)
    const float* plc;
    int nf4c, gyb;
    PREF(istart);

    for (int i = istart; i <= iend; ++i) {
        int r = rarr[i];
        const float* __restrict__ w = wp + i * WPSTRIDE;
        int mcount = ((2 * r + 17) >> 3) << 3;       // >= 2r+10, mult of 8
        __syncthreads();                             // prev conv reads done
        STOREPV(pv0, 0); STOREPV(pv1, 1); STOREPV(pv2, 2);   // vmcnt wait here
        STOREPV(pv3, 3); STOREPV(pv4, 4); STOREPV(pv5, 5);
        __syncthreads();                             // stage visible
        if (i < iend) PREF(i + 1);                   // issue next loads, no wait
        float acc[10];
#pragma unroll
        for (int k = 0; k < 10; ++k) acc[k] = 0.f;
        int base = (wv << 3) * 68 + lx;
        for (int m = 0; m < mcount; m += 8) {
            float v[8];
#pragma unroll
            for (int j = 0; j < 8; ++j) v[j] = stage[base + (m + j) * 68];
            FMAG(w, v, m);
        }
        // ---- epilogue for scale i ----
        if (i > istart) {
            int d = i - 1;
            float sg = sigmas[d];
#pragma unroll
            for (int k = 0; k < 10; ++k) {           // DoG; -inf outside image
                int gy = y0u - 1 + k;
                bool ok = xok && ((unsigned)gy < 1024u);
                gprev[k] = ok ? (gprev[k] - acc[k]) * sg : NEG;
            }
            float ym[8];
#pragma unroll
            for (int k = 0; k < 8; ++k)
                ym[k] = fmaxf(fmaxf(gprev[k], gprev[k + 1]), gprev[k + 2]);
            if (d - 1 >= jlo) {                      // emit j = d-1
                float pooled[8];
#pragma unroll
                for (int k = 0; k < 8; ++k) {
                    float pn = fmaxf(B[k], ym[k]);
                    float l  = __shfl_up(pn, 1);
                    float rr = __shfl_down(pn, 1);
                    pooled[k] = fmaxf(fmaxf(l, rr), pn);
                }
                if (xok && lane >= 1 && lane <= 62) {
                    int j = d - 1;
#pragma unroll
                    for (int k = 0; k < 8; ++k) {
                        float lm = fmaxf(pooled[k] + thr, 0.f);
                        float sm = 1.f - lm + Dprev[k] + thr;
                        float* orow = out + (((size_t)j << 20)
                                     + ((size_t)(y0u + k) << 10));
                        __builtin_nontemporal_store(lm, orow + x);
                        __builtin_nontemporal_store(sm, orow + DOG_ELEMS + x);
                    }
                }
            }
#pragma unroll
            for (int k = 0; k < 8; ++k) {
                B[k] = fmaxf(A[k], ym[k]);
                A[k] = ym[k];
                Dprev[k] = gprev[k + 1];             // dog center rows
            }
        }
#pragma unroll
        for (int k = 0; k < 10; ++k) gprev[k] = acc[k];
    }
    if (jhi == 49) {                                 // tail: j=49 (ym_50 = -inf)
        float pooled[8];
#pragma unroll
        for (int k = 0; k < 8; ++k) {
            float pn = B[k];
            float l  = __shfl_up(pn, 1);
            float rr = __shfl_down(pn, 1);
            pooled[k] = fmaxf(fmaxf(l, rr), pn);
        }
        if (xok && lane >= 1 && lane <= 62) {
#pragma unroll
            for (int k = 0; k < 8; ++k) {
                float lm = fmaxf(pooled[k] + thr, 0.f);
                float sm = 1.f - lm + Dprev[k] + thr;
                float* orow = out + (((size_t)49 << 20)
                             + ((size_t)(y0u + k) << 10));
                __builtin_nontemporal_store(lm, orow + x);
                __builtin_nontemporal_store(sm, orow + DOG_ELEMS + x);
            }
        }
    }
}

extern "C" void kernel_launch(void* const* d_in, const int* in_sizes, int n_in,
                              void* d_out, int out_size, void* d_ws, size_t ws_size,
                              hipStream_t stream) {
    const float* input  = (const float*)d_in[0];
    const float* weight = (const float*)d_in[1];
    const float* sigmas = (const float*)d_in[2];
    const float* thr    = (const float*)d_in[3];
    float* out = (float*)d_out;

    int S = 103;
    if (n_in > 1 && in_sizes[1] >= NS) {
        int s2 = in_sizes[1] / NS;
        S = (int)(sqrt((double)s2) + 0.5);
    }

    size_t need = ((size_t)NS * PLANE + NS * WPSTRIDE + 64) * 4 + 256;
    if (ws_size < need) return;   // insufficient scratch -> visible validation failure

    float* tmpH = (float*)d_ws;                    // 51 planes (214 MB)
    float* wp   = tmpH + (size_t)NS * PLANE;       // 51 * 160 floats
    int*   rarr = (int*)(wp + NS * WPSTRIDE);      // 51 ints (64 slots)

    dog_prep <<<NS, 128, 0, stream>>>(weight, wp, rarr, S);
    dog_hblur<<<dim3(512, 5), 256, 0, stream>>>(input, tmpH, wp, rarr);
    dog_fused<<<1408, 512, 0, stream>>>(tmpH, out, wp, rarr, sigmas, thr);
}

// Round 17
// 411.295 us; speedup vs baseline: 1.7933x; 1.5306x over previous
//
#include <hip/hip_runtime.h>
#include <cmath>

#define NS 51
#define ND 50
#define PLANE 1048576            // 1024*1024
#define DOG_ELEMS (ND * PLANE)   // 52428800
#define WPSTRIDE 160             // padded 1-D kernel: 17 zeros | taps | zeros

// ---------------- K0: extract normalized 1-D kernels + radii --------------------
__global__ void dog_prep(const float* __restrict__ weight,
                         float* __restrict__ wp,
                         int* __restrict__ rarr, int S) {
    int i = blockIdx.x;
    int t = threadIdx.x;
    int R = (S - 1) >> 1;
    const float* row = weight + ((size_t)i * S + R) * S;   // center row of scale i
    __shared__ float sr[128];
    __shared__ float ssum;
    __shared__ int spad;
    if (t < S) sr[t] = row[t];
    for (int j = t; j < WPSTRIDE; j += blockDim.x) wp[i * WPSTRIDE + j] = 0.f;
    __syncthreads();
    if (t == 0) {
        float sum = 0.f;
        for (int j = 0; j < S; ++j) sum += sr[j];
        int pad = 0;
        while (pad < R && sr[pad] == 0.f) ++pad;
        ssum = sum; spad = pad;
        rarr[i] = R - pad;
    }
    __syncthreads();
    int pad = spad;
    int r = R - pad;
    float inv = 1.f / ssum;
    for (int j = t; j <= 2 * r; j += blockDim.x)
        wp[i * WPSTRIDE + 17 + j] = sr[pad + j] * inv;
}

// ---------------- K1: horizontal blur (unchanged from R14) ----------------------
__global__ __launch_bounds__(256) void dog_hblur(
        const float* __restrict__ in, float* __restrict__ tmpH,
        const float* __restrict__ wp, const int* __restrict__ rarr) {
    const int lo_t[5] = {0, 17, 28, 37, 44};
    const int hi_t[5] = {17, 28, 37, 44, 51};
    int t = threadIdx.x;
    int grp = t >> 7;
    int tl = t & 127;
    int y = (blockIdx.x << 1) | grp;
    int zc = blockIdx.y;
    __shared__ float srow[2][1284];                 // 321 swizzled float4 slots
    const float* inrow = in + ((size_t)y << 10);
    for (int f = tl; f < 286; f += 128) {           // elements 4f-56 .. 4f-53
        int xg = (f << 2) - 56;
        float4 v = make_float4(0.f, 0.f, 0.f, 0.f);
        if (xg >= 0 && xg <= 1020) {
            v = *(const float4*)(inrow + xg);
        } else {
            float vv[4];
#pragma unroll
            for (int c = 0; c < 4; ++c) {
                int g = xg + c;
                vv[c] = ((unsigned)g < 1024u) ? inrow[g] : 0.f;
            }
            v = make_float4(vv[0], vv[1], vv[2], vv[3]);
        }
        int fs = f + (f >> 3);                      // swizzled float4 index
        *(float4*)&srow[grp][fs << 2] = v;
    }
    __syncthreads();
    const float* s = srow[grp];
    for (int i = lo_t[zc]; i < hi_t[zc]; ++i) {
        int r = rarr[i];
        int c0 = 56 - r;
        int d = c0 & 7;
        int c0a = c0 - d;
        const float* __restrict__ w2 = wp + i * WPSTRIDE + 17 - d;
        int mcount = ((2 * r + d + 15) >> 3) << 3;  // >= 2r+d+8, mult of 8
        float acc[8];
#pragma unroll
        for (int k = 0; k < 8; ++k) acc[k] = 0.f;
        int ft = (c0a >> 2) + (tl << 1);            // base float4 index
        for (int m = 0; m < mcount; m += 8) {
            int f  = ft + (m >> 2);
            int fa = f + (f >> 3);
            int fb = (f + 1) + ((f + 1) >> 3);
            float4 va = *(const float4*)&s[fa << 2];
            float4 vb = *(const float4*)&s[fb << 2];
            float v[8] = {va.x, va.y, va.z, va.w, vb.x, vb.y, vb.z, vb.w};
#pragma unroll
            for (int j2 = 0; j2 < 8; ++j2)
#pragma unroll
                for (int k = 0; k < 8; ++k)
                    acc[k] = fmaf(w2[m + j2 - k], v[j2], acc[k]);
        }
        float* o = tmpH + (((size_t)i) << 20) + ((size_t)y << 10) + (tl << 3);
        *(float4*)o       = make_float4(acc[0], acc[1], acc[2], acc[3]);
        *(float4*)(o + 4) = make_float4(acc[4], acc[5], acc[6], acc[7]);
    }
}

// ---------------- K2: fused vconv + DoG + 3x3x3 pool + epilogue -----------------
// ONE change vs R14: batched stage phase. All 6 staging loads issue into named
// regs, THEN all 6 ds_writes (waits become vmcnt(5..0) against in-flight loads
// -> ~1 exposed latency/scale instead of 6 serial round-trips). pv live range
// is barrier-to-barrier within one iteration (no loop-carried float4 -> no
// spill). Stores unconditional: load index clamped, stage padded to 181 rows.

#define FMAG(W, V, MM) do {                                                       \
_Pragma("unroll")                                                                 \
    for (int j_ = 0; j_ < 8; ++j_)                                                \
_Pragma("unroll")                                                                 \
        for (int k_ = 0; k_ < 10; ++k_)                                           \
            acc[k_] = fmaf((W)[17 + (MM) + j_ - k_], V[j_], acc[k_]);             \
    } while (0)

#define LOAD1(PV, KK) do {                                                        \
    int e_ = t + ((KK) << 9);                                                     \
    int ec_ = e_ < nf4 ? e_ : nf4 - 1;                                            \
    int row_ = ec_ / 17, c_ = ec_ - row_ * 17;                                    \
    int gy_ = gyb + row_;                                                         \
    int gx_ = xa + (c_ << 2);                                                     \
    float4 v_ = make_float4(0.f, 0.f, 0.f, 0.f);                                  \
    if ((unsigned)gy_ < 1024u) {                                                  \
        const float* rp_ = plane + ((size_t)gy_ << 10);                           \
        if ((unsigned)gx_ <= 1020u) {                                             \
            v_ = *(const float4*)(rp_ + gx_);                                     \
        } else {                                                                  \
            float vv_[4];                                                         \
_Pragma("unroll")                                                                 \
            for (int cc_ = 0; cc_ < 4; ++cc_) {                                   \
                int g_ = gx_ + cc_;                                               \
                vv_[cc_] = ((unsigned)g_ < 1024u) ? rp_[g_] : 0.f;                \
            }                                                                     \
            v_ = make_float4(vv_[0], vv_[1], vv_[2], vv_[3]);                     \
        }                                                                         \
    }                                                                             \
    PV = v_;                                                                      \
} while (0)

#define STORE1(PV, KK) do {                                                       \
    int e_ = t + ((KK) << 9);                                                     \
    int row_ = e_ / 17, c_ = e_ - row_ * 17;                                      \
    *(float4*)(stage + row_ * 68 + (c_ << 2)) = PV;                               \
} while (0)

__global__ __launch_bounds__(512, 6) void dog_fused(
        const float* __restrict__ tmpH, float* __restrict__ out,
        const float* __restrict__ wp, const int* __restrict__ rarr,
        const float* __restrict__ sigmas, const float* __restrict__ thr_p) {
    const int jlo_t[5] = {0, 17, 28, 37, 44};
    const int jhi_t[5] = {16, 27, 36, 43, 49};
    int p = blockIdx.x;                   // 0..1407
    int xcd = p & 7;
    int q = p >> 3;                       // 0..175
    int c8 = q >> 4;                      // 0..10
    int ybg = q & 15;                     // 0..15  (same-XCD consecutive y-blocks)
    int combo = (c8 << 3) | xcd;          // 0..87
    if (combo >= 85) return;              // pad blocks
    int wx = combo % 17;                  // 0..16
    int zc = combo / 17;                  // 0..4
    int t = threadIdx.x;
    int lane = t & 63;
    int wv = t >> 6;                      // 0..7
    int y0u = __builtin_amdgcn_readfirstlane((ybg << 6) + (wv << 3));
    int x0 = wx * 62 - 1;
    int x = x0 + lane;                    // -1 .. 1054
    int xa = x0 & ~3;                     // 4-aligned stage base col
    int lx = (x0 - xa) + lane;            // lane's col in stage [0..66]
    bool xok = ((unsigned)x < 1024u);
    float thr = thr_p[0];
    const float NEG = -__builtin_huge_valf();

    __shared__ float stage[181 * 68];     // 49.2 KB (181 rows: unconditional stores)

    int jlo = jlo_t[zc], jhi = jhi_t[zc];
    int istart = jlo > 0 ? jlo - 1 : 0;
    int iend = (jhi + 2 < 50) ? jhi + 2 : 50;

    float gprev[10], A[8], B[8], Dprev[8];
#pragma unroll
    for (int k = 0; k < 10; ++k) gprev[k] = 0.f;
#pragma unroll
    for (int k = 0; k < 8; ++k) { A[k] = NEG; B[k] = NEG; Dprev[k] = 0.f; }

    for (int i = istart; i <= iend; ++i) {
        int r = rarr[i];
        const float* __restrict__ w = wp + i * WPSTRIDE;
        const float* __restrict__ plane = tmpH + ((size_t)i << 20);
        int mcount = ((2 * r + 17) >> 3) << 3;       // >= 2r+10, mult of 8
        int nf4 = (mcount + 64) * 17;                // <= 176*17 = 2992
        int gyb = (ybg << 6) - 1 - r;
        __syncthreads();                             // prev conv reads done
        {   // batched stage: issue 6 loads, then 6 LDS writes (short live range)
            float4 pv0, pv1, pv2, pv3, pv4, pv5;
            LOAD1(pv0, 0); LOAD1(pv1, 1); LOAD1(pv2, 2);
            LOAD1(pv3, 3); LOAD1(pv4, 4); LOAD1(pv5, 5);
            STORE1(pv0, 0); STORE1(pv1, 1); STORE1(pv2, 2);
            STORE1(pv3, 3); STORE1(pv4, 4); STORE1(pv5, 5);
        }
        __syncthreads();                             // stage visible
        float acc[10];
#pragma unroll
        for (int k = 0; k < 10; ++k) acc[k] = 0.f;
        int base = (wv << 3) * 68 + lx;
        for (int m = 0; m < mcount; m += 8) {
            float v[8];
#pragma unroll
            for (int j = 0; j < 8; ++j) v[j] = stage[base + (m + j) * 68];
            FMAG(w, v, m);
        }
        // ---- epilogue for scale i ----
        if (i > istart) {
            int d = i - 1;
            float sg = sigmas[d];
#pragma unroll
            for (int k = 0; k < 10; ++k) {           // DoG; -inf outside image
                int gy = y0u - 1 + k;
                bool ok = xok && ((unsigned)gy < 1024u);
                gprev[k] = ok ? (gprev[k] - acc[k]) * sg : NEG;
            }
            float ym[8];
#pragma unroll
            for (int k = 0; k < 8; ++k)
                ym[k] = fmaxf(fmaxf(gprev[k], gprev[k + 1]), gprev[k + 2]);
            if (d - 1 >= jlo) {                      // emit j = d-1
                float pooled[8];
#pragma unroll
                for (int k = 0; k < 8; ++k) {
                    float pn = fmaxf(B[k], ym[k]);
                    float l  = __shfl_up(pn, 1);
                    float rr = __shfl_down(pn, 1);
                    pooled[k] = fmaxf(fmaxf(l, rr), pn);
                }
                if (xok && lane >= 1 && lane <= 62) {
                    int j = d - 1;
#pragma unroll
                    for (int k = 0; k < 8; ++k) {
                        float lm = fmaxf(pooled[k] + thr, 0.f);
                        float sm = 1.f - lm + Dprev[k] + thr;
                        float* orow = out + (((size_t)j << 20)
                                     + ((size_t)(y0u + k) << 10));
                        __builtin_nontemporal_store(lm, orow + x);
                        __builtin_nontemporal_store(sm, orow + DOG_ELEMS + x);
                    }
                }
            }
#pragma unroll
            for (int k = 0; k < 8; ++k) {
                B[k] = fmaxf(A[k], ym[k]);
                A[k] = ym[k];
                Dprev[k] = gprev[k + 1];             // dog center rows
            }
        }
#pragma unroll
        for (int k = 0; k < 10; ++k) gprev[k] = acc[k];
    }
    if (jhi == 49) {                                 // tail: j=49 (ym_50 = -inf)
        float pooled[8];
#pragma unroll
        for (int k = 0; k < 8; ++k) {
            float pn = B[k];
            float l  = __shfl_up(pn, 1);
            float rr = __shfl_down(pn, 1);
            pooled[k] = fmaxf(fmaxf(l, rr), pn);
        }
        if (xok && lane >= 1 && lane <= 62) {
#pragma unroll
            for (int k = 0; k < 8; ++k) {
                float lm = fmaxf(pooled[k] + thr, 0.f);
                float sm = 1.f - lm + Dprev[k] + thr;
                float* orow = out + (((size_t)49 << 20)
                             + ((size_t)(y0u + k) << 10));
                __builtin_nontemporal_store(lm, orow + x);
                __builtin_nontemporal_store(sm, orow + DOG_ELEMS + x);
            }
        }
    }
}

extern "C" void kernel_launch(void* const* d_in, const int* in_sizes, int n_in,
                              void* d_out, int out_size, void* d_ws, size_t ws_size,
                              hipStream_t stream) {
    const float* input  = (const float*)d_in[0];
    const float* weight = (const float*)d_in[1];
    const float* sigmas = (const float*)d_in[2];
    const float* thr    = (const float*)d_in[3];
    float* out = (float*)d_out;

    int S = 103;
    if (n_in > 1 && in_sizes[1] >= NS) {
        int s2 = in_sizes[1] / NS;
        S = (int)(sqrt((double)s2) + 0.5);
    }

    size_t need = ((size_t)NS * PLANE + NS * WPSTRIDE + 64) * 4 + 256;
    if (ws_size < need) return;   // insufficient scratch -> visible validation failure

    float* tmpH = (float*)d_ws;                    // 51 planes (214 MB)
    float* wp   = tmpH + (size_t)NS * PLANE;       // 51 * 160 floats
    int*   rarr = (int*)(wp + NS * WPSTRIDE);      // 51 ints (64 slots)

    dog_prep <<<NS, 128, 0, stream>>>(weight, wp, rarr, S);
    dog_hblur<<<dim3(512, 5), 256, 0, stream>>>(input, tmpH, wp, rarr);
    dog_fused<<<1408, 512, 0, stream>>>(tmpH, out, wp, rarr, sigmas, thr);
}